// Round 1
// baseline (16151.685 us; speedup 1.0000x reference)
//
#include <hip/hip_runtime.h>

#define EPS 1e-5f

__device__ __forceinline__ float logsig(float z) {
    return fminf(z, 0.0f) - log1pf(__expf(-fabsf(z)));
}

// One block = one sequence. 1024 threads = 16 waves (4 waves/EU).
// LDS ~155 KB pins 1 workgroup/CU; doubling threads/workgroup doubles resident
// waves 8->16 without touching the LDS budget (the previous 512-thread version
// sat at 2 waves/EU, VALUBusy 30% = latency-bound).
// Role split: lower 8 waves (grp==0) own recurrent state S and run
// gate-cumsum -> Q/K proj -> attention; upper 8 waves (grp==1) run V proj,
// R proj (kept in regs until the silu apply), next-slab prefetch (issue in F1
// phase, LDS-write in F2a phase) and next-chunk LN stats (during F2b phase).
// All __syncthreads() are at top level (convergent). 1024-thread blocks force
// VGPR<=128 (same cap the 512-thread version compiled to).
template<int SLEN, int PSTRIDE>
__global__ __launch_bounds__(1024)
void gla_pass(const float* __restrict__ src, float* __restrict__ out,
              const float* __restrict__ gamma, const float* __restrict__ beta,
              const float* __restrict__ Wq, const float* __restrict__ Wk,
              const float* __restrict__ Wv, const float* __restrict__ Wg1,
              const float* __restrict__ Wg2, const float* __restrict__ Wr,
              const float* __restrict__ gn, const float* __restrict__ Wo,
              const float* __restrict__ ctw, const float* __restrict__ ctb)
{
    constexpr int NC = SLEN / 32;
    constexpr int L  = SLEN - 1;

    __shared__ __align__(16) float sxc[64][36];   // LN'd slab window (33 cols used)
    __shared__ __align__(16) float sxr[64][32];   // raw slab (residual source)
    __shared__ __align__(16) float qf[32][256];   // q*Dk^-0.5 * exp(gc)
    __shared__ __align__(16) float kf[32][256];   // k * exp(-gc)
    __shared__ __align__(16) float voc[32][256];  // v -> oe1 partial -> o -> o*silu(r)
    __shared__ __align__(16) float uni[8832];     // Ats[4][32][36] + gdec[32][132]
    __shared__ __align__(16) float fw1t[32][36];  // (f @ Wg1)^T : fw1t[m][t]
    __shared__ __align__(16) float gprevs[128];   // deconv carry row
    __shared__ float egl[256];                    // exp(chunk-total gate)
    __shared__ float sgam[64], sbet[64];
    __shared__ float smu[33], sinv[33];
    __shared__ float gcarry[256];                 // gate cumsum carry

    float* const Ats  = uni;          // h*1152 + t*36 + s
    float* const gdec = uni + 4608;   // row*132 + c

    const int tid  = threadIdx.x;     // 0..1023
    const int lane = tid & 63;
    const int wv   = tid >> 6;        // 0..15
    const int grp  = tid >> 9;        // 0 = state/attn group, 1 = V/R/prefetch group
    const int t512 = tid & 511;
    const int h    = (t512 >> 6) & 3; // head (grp 0)
    const int kh   = (t512 >> 8) & 1; // k-half (grp 0)
    const int d    = tid & 255;       // column for (d, th) stages
    const int th   = (tid >> 8) & 1;  // per-group t-half (rows th*16 .. th*16+15)
    const int n    = blockIdx.x;

    int b, fixedoff;
    if constexpr (PSTRIDE == 1) { b = n >> 8; fixedoff = (n & 255) * 128; }
    else                        { b = n >> 7; fixedoff = (n & 127); }
    const int cbase = (b * 64) * 32768 + fixedoff;

    if (tid < 64)  { sgam[tid] = gamma[tid]; sbet[tid] = beta[tid]; }
    if (tid < 128) gprevs[tid] = 0.0f;

    float S[32];
    #pragma unroll
    for (int k = 0; k < 32; ++k) S[k] = 0.0f;

    const float gnv  = gn[h * 64 + lane];
    const float bias = ctb[lane];

    // ---- prologue: chunk-0 slab -> sxc (raw) ----
    #pragma unroll
    for (int k = 0; k < 3; ++k) {
        int idx = tid + k * 1024;
        if (idx < 64 * 33) {
            int cc = idx / 33, i = idx - cc * 33;
            int p = i; if (p > SLEN - 1) p = SLEN - 1;
            sxc[cc][i] = src[cbase + cc * 32768 + p * PSTRIDE];
        }
    }

    for (int ch = 0; ch < NC; ++ch) {
        const int l0 = ch * 32;
        __syncthreads();               // sxc(ch) raw ready (prologue or prefetch)

        if (ch == 0) {
            // LN stats for chunk 0, wave-parallel (16 waves x ~2 cols, shfl tree)
            for (int col = wv; col < 33; col += 16) {
                float x = sxc[lane][col];
                float s1 = x, s2 = x * x;
                #pragma unroll
                for (int off = 32; off > 0; off >>= 1) {
                    s1 += __shfl_xor(s1, off, 64);
                    s2 += __shfl_xor(s2, off, 64);
                }
                if (lane == 0) {
                    float mu  = s1 * (1.0f / 64.0f);
                    float var = s2 * (1.0f / 64.0f) - mu * mu;
                    smu[col]  = mu;
                    sinv[col] = rsqrtf(fmaxf(var, 0.0f) + EPS);
                }
            }
            __syncthreads();
        }

        // ---- P2: raw->sxr copy fused with in-place normalize (element-wise) ----
        #pragma unroll
        for (int k = 0; k < 3; ++k) {
            int idx = tid + k * 1024;
            if (idx < 64 * 33) {
                int cc = idx / 33, i = idx - cc * 33;
                float x = sxc[cc][i];
                if (i < 32) sxr[cc][i] = x;
                sxc[cc][i] = (x - smu[i]) * sinv[i] * sgam[cc] + sbet[cc];
            }
        }
        __syncthreads();

        // ---- P3: fw1t[m][t] = (f @ Wg1)^T, one output per thread ----
        {
            const int m = tid & 31, t = tid >> 5;   // t in 0..31
            float a = 0.0f;
            for (int cc = 0; cc < 64; ++cc)
                a += sxc[cc][t]     * Wg1[(2*cc)*32 + m]
                   + sxc[cc][t + 1] * Wg1[(2*cc+1)*32 + m];
            fw1t[m][t] = a;
        }
        __syncthreads();

        // t16: grp0 = gate log-cumsum "run"; grp1 = V accumulator "av" (union
        // keeps static VGPR pressure at the 512-thread version's level).
        float t16[16];
        float ar[16];                 // grp1: R accumulator, lives until P9

        // ---- P4: grp0 = gate cumsum part 1 | grp1 = V proj (cc 0..31) ----
        if (grp == 0) {
            const int t0 = th * 16;
            #pragma unroll
            for (int t = 0; t < 16; ++t) t16[t] = 0.0f;
            for (int mm = 0; mm < 32; ++mm) {
                const float w = Wg2[mm * 256 + d];
                #pragma unroll
                for (int i = 0; i < 4; ++i) {
                    float4 f4 = *(const float4*)&fw1t[mm][t0 + 4 * i];
                    t16[4*i+0] += f4.x * w; t16[4*i+1] += f4.y * w;
                    t16[4*i+2] += f4.z * w; t16[4*i+3] += f4.w * w;
                }
            }
            float r = 0.0f;
            #pragma unroll
            for (int t = 0; t < 16; ++t) {
                if ((l0 + t0 + t) < L) r += logsig(t16[t]) * (1.0f / 32.0f);
                t16[t] = r;                    // local cumsum
            }
            if (th == 0) gcarry[d] = r;
        } else {
            const int t0 = th * 16;
            #pragma unroll
            for (int t = 0; t < 16; ++t) t16[t] = 0.0f;
            for (int cc = 0; cc < 32; ++cc) {
                float col[17];
                #pragma unroll
                for (int i = 0; i < 4; ++i) {
                    float4 c4 = *(const float4*)&sxc[cc][t0 + 4 * i];
                    col[4*i] = c4.x; col[4*i+1] = c4.y; col[4*i+2] = c4.z; col[4*i+3] = c4.w;
                }
                col[16] = sxc[cc][t0 + 16];
                const float wv0 = Wv[(2*cc)*256 + d], wv1 = Wv[(2*cc+1)*256 + d];
                #pragma unroll
                for (int t = 0; t < 16; ++t) t16[t] += col[t] * wv0 + col[t+1] * wv1;
            }
        }
        __syncthreads();

        // ---- P5: grp0 = finish gate + Q/K proj | grp1 = V (cc 32..63) + store + R proj ----
        if (grp == 0) {
            const int t0 = th * 16;
            const float c = (th == 0) ? 0.0f : gcarry[d];
            #pragma unroll
            for (int t = 0; t < 16; ++t) t16[t] += c;    // full cumsum
            if (th == 1) egl[d] = __expf(t16[15]);
            float aq[16], ak[16];
            #pragma unroll
            for (int t = 0; t < 16; ++t) { aq[t] = 0.0f; ak[t] = 0.0f; }
            for (int cc = 0; cc < 64; ++cc) {
                float col[17];
                #pragma unroll
                for (int i = 0; i < 4; ++i) {
                    float4 c4 = *(const float4*)&sxc[cc][t0 + 4 * i];
                    col[4*i] = c4.x; col[4*i+1] = c4.y; col[4*i+2] = c4.z; col[4*i+3] = c4.w;
                }
                col[16] = sxc[cc][t0 + 16];
                const float wq0 = Wq[(2*cc)*256 + d], wq1 = Wq[(2*cc+1)*256 + d];
                const float wk0 = Wk[(2*cc)*256 + d], wk1 = Wk[(2*cc+1)*256 + d];
                #pragma unroll
                for (int t = 0; t < 16; ++t) {
                    aq[t] += col[t] * wq0 + col[t+1] * wq1;
                    ak[t] += col[t] * wk0 + col[t+1] * wk1;
                }
            }
            #pragma unroll
            for (int t = 0; t < 16; ++t) {
                bool valid = (l0 + t0 + t) < L;
                float ep = __expf(t16[t]);
                float em = __expf(-t16[t]);
                qf[t0 + t][d] = valid ? aq[t] * 0.125f * ep : 0.0f;
                kf[t0 + t][d] = valid ? ak[t] * em : 0.0f;
            }
        } else {
            const int t0 = th * 16;
            for (int cc = 32; cc < 64; ++cc) {
                float col[17];
                #pragma unroll
                for (int i = 0; i < 4; ++i) {
                    float4 c4 = *(const float4*)&sxc[cc][t0 + 4 * i];
                    col[4*i] = c4.x; col[4*i+1] = c4.y; col[4*i+2] = c4.z; col[4*i+3] = c4.w;
                }
                col[16] = sxc[cc][t0 + 16];
                const float wv0 = Wv[(2*cc)*256 + d], wv1 = Wv[(2*cc+1)*256 + d];
                #pragma unroll
                for (int t = 0; t < 16; ++t) t16[t] += col[t] * wv0 + col[t+1] * wv1;
            }
            #pragma unroll
            for (int t = 0; t < 16; ++t)
                voc[t0 + t][d] = ((l0 + t0 + t) < L) ? t16[t] : 0.0f;
            // R projection; result applied to voc at P9
            #pragma unroll
            for (int t = 0; t < 16; ++t) ar[t] = 0.0f;
            for (int cc = 0; cc < 64; ++cc) {
                float col[17];
                #pragma unroll
                for (int i = 0; i < 4; ++i) {
                    float4 c4 = *(const float4*)&sxc[cc][t0 + 4 * i];
                    col[4*i] = c4.x; col[4*i+1] = c4.y; col[4*i+2] = c4.z; col[4*i+3] = c4.w;
                }
                col[16] = sxc[cc][t0 + 16];
                const float w0 = Wr[(2*cc)*256 + d], w1 = Wr[(2*cc+1)*256 + d];
                #pragma unroll
                for (int t = 0; t < 16; ++t) ar[t] += col[t] * w0 + col[t+1] * w1;
            }
        }
        __syncthreads();               // qf, kf, voc ready

        // ---- P6: grp0 = vcol snapshot + triangular scores | grp1 = prefetch issue ----
        float vcol[32];                // grp0
        float pre[5];                  // grp1 staging regs
        if (grp == 0) {
            const int base = h * 64;
            #pragma unroll
            for (int t = 0; t < 32; ++t) vcol[t] = voc[t][base + lane];
            for (int pi = lane + 64 * kh; pi < 528; pi += 128) {
                float fpi = (float)pi;
                int t = (int)((sqrtf(8.0f * fpi + 1.0f) - 1.0f) * 0.5f);
                if (((t + 1) * (t + 2)) / 2 <= pi) ++t;
                if ((t * (t + 1)) / 2 > pi) --t;
                int s = pi - (t * (t + 1)) / 2;
                float a = 0.0f;
                #pragma unroll
                for (int ii = 0; ii < 16; ++ii) {
                    int i = (ii + lane) & 15;
                    float4 q4 = *(const float4*)&qf[t][base + 4 * i];
                    float4 k4 = *(const float4*)&kf[s][base + 4 * i];
                    a += q4.x*k4.x + q4.y*k4.y + q4.z*k4.z + q4.w*k4.w;
                }
                Ats[h * 1152 + t * 36 + s] = a;
            }
        } else if (ch + 1 < NC) {
            const int l0n = l0 + 32;
            #pragma unroll
            for (int k = 0; k < 5; ++k) {
                int idx = t512 + k * 512;
                if (idx < 64 * 33) {
                    int cc = idx / 33, i = idx - cc * 33;
                    int p = l0n + i; if (p > SLEN - 1) p = SLEN - 1;
                    pre[k] = src[cbase + cc * 32768 + p * PSTRIDE];
                }
            }
        }
        __syncthreads();               // Ats ready; vcol snapped (voc dead as v)

        // ---- P7: kh1 = o_inter partial (pre-update S rows 32..63) -> voc
        //          | grp1 = write prefetched slab into sxc (sxc dead since P5) ----
        if (grp == 0) {
            if (kh == 1) {
                const int base = h * 64;
                #pragma unroll
                for (int t = 0; t < 32; ++t) {
                    float oe = 0.0f;
                    #pragma unroll
                    for (int i = 0; i < 8; ++i) {
                        float4 q4 = *(const float4*)&qf[t][base + 32 + 4 * i];
                        oe += q4.x*S[4*i] + q4.y*S[4*i+1] + q4.z*S[4*i+2] + q4.w*S[4*i+3];
                    }
                    voc[t][base + lane] = oe;
                }
            }
        } else if (ch + 1 < NC) {
            #pragma unroll
            for (int k = 0; k < 5; ++k) {
                int idx = t512 + k * 512;
                if (idx < 64 * 33) {
                    int cc = idx / 33, i = idx - cc * 33;
                    sxc[cc][i] = pre[k];
                }
            }
        }
        __syncthreads();               // oe1 partials in voc; next slab in sxc

        // ---- P8: kh0 = finalize o (oe0 + o_intra + RMS) | kh1 = S update rows 32..63
        //          | grp1 = LN stats for next chunk ----
        if (grp == 0) {
            const int base = h * 64;
            if (kh == 0) {
                #pragma unroll
                for (int t = 0; t < 32; ++t) {
                    float ot = voc[t][base + lane];
                    #pragma unroll
                    for (int i = 0; i < 8; ++i) {
                        float4 q4 = *(const float4*)&qf[t][base + 4 * i];
                        ot += q4.x*S[4*i] + q4.y*S[4*i+1] + q4.z*S[4*i+2] + q4.w*S[4*i+3];
                    }
                    const float* arow = &Ats[h * 1152 + t * 36];
                    #pragma unroll
                    for (int s4 = 0; s4 + 4 <= t + 1; s4 += 4) {
                        float4 a4 = *(const float4*)&arow[s4];
                        ot += a4.x*vcol[s4] + a4.y*vcol[s4+1] + a4.z*vcol[s4+2] + a4.w*vcol[s4+3];
                    }
                    #pragma unroll
                    for (int s = (t + 1) & ~3; s <= t; ++s) ot += arow[s] * vcol[s];
                    float ss = ot * ot;
                    #pragma unroll
                    for (int off = 32; off > 0; off >>= 1) ss += __shfl_xor(ss, off, 64);
                    voc[t][base + lane] = ot * rsqrtf(ss * (1.0f / 64.0f) + EPS) * gnv;
                }
            } else {
                const int kb = base + 32;
                #pragma unroll
                for (int i = 0; i < 8; ++i) {
                    float s0 = 0.0f, s1 = 0.0f, s2 = 0.0f, s3 = 0.0f;
                    #pragma unroll
                    for (int t = 0; t < 32; ++t) {
                        float4 k4 = *(const float4*)&kf[t][kb + 4 * i];
                        const float vt = vcol[t];
                        s0 += k4.x * vt; s1 += k4.y * vt; s2 += k4.z * vt; s3 += k4.w * vt;
                    }
                    S[4*i+0] = egl[kb + 4*i+0] * (S[4*i+0] + s0);
                    S[4*i+1] = egl[kb + 4*i+1] * (S[4*i+1] + s1);
                    S[4*i+2] = egl[kb + 4*i+2] * (S[4*i+2] + s2);
                    S[4*i+3] = egl[kb + 4*i+3] * (S[4*i+3] + s3);
                }
            }
        } else if (ch + 1 < NC) {
            for (int col = wv - 8; col < 33; col += 8) {
                float x = sxc[lane][col];
                float s1 = x, s2 = x * x;
                #pragma unroll
                for (int off = 32; off > 0; off >>= 1) {
                    s1 += __shfl_xor(s1, off, 64);
                    s2 += __shfl_xor(s2, off, 64);
                }
                if (lane == 0) {
                    float mu  = s1 * (1.0f / 64.0f);
                    float var = s2 * (1.0f / 64.0f) - mu * mu;
                    smu[col]  = mu;
                    sinv[col] = rsqrtf(fmaxf(var, 0.0f) + EPS);
                }
            }
        }
        __syncthreads();               // final o in voc

        // ---- P9: kh0 = S update rows 0..31 | grp1 = voc *= silu(r) ----
        if (grp == 0) {
            if (kh == 0) {
                const int kb = h * 64;
                #pragma unroll
                for (int i = 0; i < 8; ++i) {
                    float s0 = 0.0f, s1 = 0.0f, s2 = 0.0f, s3 = 0.0f;
                    #pragma unroll
                    for (int t = 0; t < 32; ++t) {
                        float4 k4 = *(const float4*)&kf[t][kb + 4 * i];
                        const float vt = vcol[t];
                        s0 += k4.x * vt; s1 += k4.y * vt; s2 += k4.z * vt; s3 += k4.w * vt;
                    }
                    S[4*i+0] = egl[kb + 4*i+0] * (S[4*i+0] + s0);
                    S[4*i+1] = egl[kb + 4*i+1] * (S[4*i+1] + s1);
                    S[4*i+2] = egl[kb + 4*i+2] * (S[4*i+2] + s2);
                    S[4*i+3] = egl[kb + 4*i+3] * (S[4*i+3] + s3);
                }
            }
        } else {
            const int t0 = th * 16;
            #pragma unroll
            for (int t = 0; t < 16; ++t) {
                const float r = ar[t];
                voc[t0 + t][d] *= r / (1.0f + __expf(-r));
            }
        }
        __syncthreads();               // voc = o * silu(r)

        // ---- P10: gdec = oc @ Wo (1024 threads: 1 col x 4 rows each) ----
        {
            const int m2 = tid & 127;
            const int rg = tid >> 7;         // 0..7
            float acc[4] = {0, 0, 0, 0};
            for (int j = 0; j < 256; j += 4) {
                float w0 = Wo[(j+0)*128 + m2];
                float w1 = Wo[(j+1)*128 + m2];
                float w2 = Wo[(j+2)*128 + m2];
                float w3 = Wo[(j+3)*128 + m2];
                #pragma unroll
                for (int i = 0; i < 4; ++i) {
                    float4 o4 = *(const float4*)&voc[rg * 4 + i][j];
                    acc[i] += o4.x*w0 + o4.y*w1 + o4.z*w2 + o4.w*w3;
                }
            }
            #pragma unroll
            for (int i = 0; i < 4; ++i)
                gdec[(rg * 4 + i) * 132 + m2] = acc[i];
        }
        __syncthreads();

        // ---- P11: deconv1d (K=2) + bias + residual + store (2 rows/thread) ----
        {
            const int o  = tid & 63;
            const int pg = tid >> 6;         // 0..15 -> rows pg*2, pg*2+1
            const float2* ctw2 = (const float2*)ctw;
            float a0 = 0.0f, a1 = 0.0f;
            for (int c4 = 0; c4 < 128; c4 += 4) {
                float2 w0 = ctw2[(c4+0)*64 + o];
                float2 w1 = ctw2[(c4+1)*64 + o];
                float2 w2 = ctw2[(c4+2)*64 + o];
                float2 w3 = ctw2[(c4+3)*64 + o];
                float4 rm = (pg == 0) ? *(const float4*)&gprevs[c4]
                                      : *(const float4*)&gdec[(pg*2 - 1) * 132 + c4];
                float4 r0 = *(const float4*)&gdec[(pg*2 + 0) * 132 + c4];
                float4 r1 = *(const float4*)&gdec[(pg*2 + 1) * 132 + c4];
                a0 += r0.x*w0.x + rm.x*w0.y + r0.y*w1.x + rm.y*w1.y
                    + r0.z*w2.x + rm.z*w2.y + r0.w*w3.x + rm.w*w3.y;
                a1 += r1.x*w0.x + r0.x*w0.y + r1.y*w1.x + r0.y*w1.y
                    + r1.z*w2.x + r0.z*w2.y + r1.w*w3.x + r0.w*w3.y;
            }
            const int tl = pg * 2;
            out[cbase + o * 32768 + (l0 + tl    ) * PSTRIDE] = a0 + bias + sxr[o][tl];
            out[cbase + o * 32768 + (l0 + tl + 1) * PSTRIDE] = a1 + bias + sxr[o][tl + 1];
        }
        __syncthreads();
        if (tid < 128) gprevs[tid] = gdec[31 * 132 + tid];
    }
}

extern "C" void kernel_launch(void* const* d_in, const int* in_sizes, int n_in,
                              void* d_out, int out_size, void* d_ws, size_t ws_size,
                              hipStream_t stream)
{
    const float* x = (const float*)d_in[0];
    float* y = (float*)d_ws;     // intra output: 4*64*256*128 fp32
    float* z = (float*)d_out;

    gla_pass<128, 1><<<dim3(1024), dim3(1024), 0, stream>>>(
        x, y,
        (const float*)d_in[2],  (const float*)d_in[3],  (const float*)d_in[4],
        (const float*)d_in[5],  (const float*)d_in[6],  (const float*)d_in[7],
        (const float*)d_in[8],  (const float*)d_in[9],  (const float*)d_in[10],
        (const float*)d_in[11], (const float*)d_in[12], (const float*)d_in[13]);

    gla_pass<256, 128><<<dim3(512), dim3(1024), 0, stream>>>(
        y, z,
        (const float*)d_in[14], (const float*)d_in[15], (const float*)d_in[16],
        (const float*)d_in[17], (const float*)d_in[18], (const float*)d_in[19],
        (const float*)d_in[20], (const float*)d_in[21], (const float*)d_in[22],
        (const float*)d_in[23], (const float*)d_in[24], (const float*)d_in[25]);
}

// Round 2
// 16031.062 us; speedup vs baseline: 1.0075x; 1.0075x over previous
//
#include <hip/hip_runtime.h>

#define EPS 1e-5f

__device__ __forceinline__ float logsig(float z) {
    return fminf(z, 0.0f) - log1pf(__expf(-fabsf(z)));
}

// One block = one sequence. 1024 threads = 16 waves (4 waves/EU).
// LDS ~155 KB pins 1 workgroup/CU; 16 waves double residency vs the 512-thread
// version at zero LDS cost.
// CRITICAL: the backend's default for 1024-thread kernels budgets VGPRs for
// 2 workgroups/CU (cap 64) -> R1 spilled every per-thread array to scratch
// (FETCH 1.9e6->6.0e6 KB, WRITE 1.6e6->6.9e6 KB, VALUBusy 15%). LDS already
// pins 1 wg/CU, so state the true occupancy: waves_per_eu(4,4) -> 512-reg
// pool / 4 waves = 128 VGPRs/wave, same budget the 512-thread version used.
// Role split: lower 8 waves (grp==0) own recurrent state S and run
// gate-cumsum -> Q/K proj -> attention; upper 8 waves (grp==1) run V proj,
// R proj (kept in regs until the silu apply), next-slab prefetch (issue in F1
// phase, LDS-write in F2a phase) and next-chunk LN stats (during F2b phase).
// All __syncthreads() are at top level (convergent).
template<int SLEN, int PSTRIDE>
__global__ __launch_bounds__(1024)
__attribute__((amdgpu_waves_per_eu(4, 4)))
void gla_pass(const float* __restrict__ src, float* __restrict__ out,
              const float* __restrict__ gamma, const float* __restrict__ beta,
              const float* __restrict__ Wq, const float* __restrict__ Wk,
              const float* __restrict__ Wv, const float* __restrict__ Wg1,
              const float* __restrict__ Wg2, const float* __restrict__ Wr,
              const float* __restrict__ gn, const float* __restrict__ Wo,
              const float* __restrict__ ctw, const float* __restrict__ ctb)
{
    constexpr int NC = SLEN / 32;
    constexpr int L  = SLEN - 1;

    __shared__ __align__(16) float sxc[64][36];   // LN'd slab window (33 cols used)
    __shared__ __align__(16) float sxr[64][32];   // raw slab (residual source)
    __shared__ __align__(16) float qf[32][256];   // q*Dk^-0.5 * exp(gc)
    __shared__ __align__(16) float kf[32][256];   // k * exp(-gc)
    __shared__ __align__(16) float voc[32][256];  // v -> oe1 partial -> o -> o*silu(r)
    __shared__ __align__(16) float uni[8832];     // Ats[4][32][36] + gdec[32][132]
    __shared__ __align__(16) float fw1t[32][36];  // (f @ Wg1)^T : fw1t[m][t]
    __shared__ __align__(16) float gprevs[128];   // deconv carry row
    __shared__ float egl[256];                    // exp(chunk-total gate)
    __shared__ float sgam[64], sbet[64];
    __shared__ float smu[33], sinv[33];
    __shared__ float gcarry[256];                 // gate cumsum carry

    float* const Ats  = uni;          // h*1152 + t*36 + s
    float* const gdec = uni + 4608;   // row*132 + c

    const int tid  = threadIdx.x;     // 0..1023
    const int lane = tid & 63;
    const int wv   = tid >> 6;        // 0..15
    const int grp  = tid >> 9;        // 0 = state/attn group, 1 = V/R/prefetch group
    const int t512 = tid & 511;
    const int h    = (t512 >> 6) & 3; // head (grp 0)
    const int kh   = (t512 >> 8) & 1; // k-half (grp 0)
    const int d    = tid & 255;       // column for (d, th) stages
    const int th   = (tid >> 8) & 1;  // per-group t-half (rows th*16 .. th*16+15)
    const int n    = blockIdx.x;

    int b, fixedoff;
    if constexpr (PSTRIDE == 1) { b = n >> 8; fixedoff = (n & 255) * 128; }
    else                        { b = n >> 7; fixedoff = (n & 127); }
    const int cbase = (b * 64) * 32768 + fixedoff;

    if (tid < 64)  { sgam[tid] = gamma[tid]; sbet[tid] = beta[tid]; }
    if (tid < 128) gprevs[tid] = 0.0f;

    float S[32];
    #pragma unroll
    for (int k = 0; k < 32; ++k) S[k] = 0.0f;

    const float gnv  = gn[h * 64 + lane];
    const float bias = ctb[lane];

    // ---- prologue: chunk-0 slab -> sxc (raw) ----
    #pragma unroll
    for (int k = 0; k < 3; ++k) {
        int idx = tid + k * 1024;
        if (idx < 64 * 33) {
            int cc = idx / 33, i = idx - cc * 33;
            int p = i; if (p > SLEN - 1) p = SLEN - 1;
            sxc[cc][i] = src[cbase + cc * 32768 + p * PSTRIDE];
        }
    }

    for (int ch = 0; ch < NC; ++ch) {
        const int l0 = ch * 32;
        __syncthreads();               // sxc(ch) raw ready (prologue or prefetch)

        if (ch == 0) {
            // LN stats for chunk 0, wave-parallel (16 waves x ~2 cols, shfl tree)
            for (int col = wv; col < 33; col += 16) {
                float x = sxc[lane][col];
                float s1 = x, s2 = x * x;
                #pragma unroll
                for (int off = 32; off > 0; off >>= 1) {
                    s1 += __shfl_xor(s1, off, 64);
                    s2 += __shfl_xor(s2, off, 64);
                }
                if (lane == 0) {
                    float mu  = s1 * (1.0f / 64.0f);
                    float var = s2 * (1.0f / 64.0f) - mu * mu;
                    smu[col]  = mu;
                    sinv[col] = rsqrtf(fmaxf(var, 0.0f) + EPS);
                }
            }
            __syncthreads();
        }

        // ---- P2: raw->sxr copy fused with in-place normalize (element-wise) ----
        #pragma unroll
        for (int k = 0; k < 3; ++k) {
            int idx = tid + k * 1024;
            if (idx < 64 * 33) {
                int cc = idx / 33, i = idx - cc * 33;
                float x = sxc[cc][i];
                if (i < 32) sxr[cc][i] = x;
                sxc[cc][i] = (x - smu[i]) * sinv[i] * sgam[cc] + sbet[cc];
            }
        }
        __syncthreads();

        // ---- P3: fw1t[m][t] = (f @ Wg1)^T, one output per thread ----
        {
            const int m = tid & 31, t = tid >> 5;   // t in 0..31
            float a = 0.0f;
            for (int cc = 0; cc < 64; ++cc)
                a += sxc[cc][t]     * Wg1[(2*cc)*32 + m]
                   + sxc[cc][t + 1] * Wg1[(2*cc+1)*32 + m];
            fw1t[m][t] = a;
        }
        __syncthreads();

        // t16: grp0 = gate log-cumsum "run"; grp1 = V accumulator "av" (union
        // keeps static VGPR pressure at the 512-thread version's level).
        float t16[16];
        float ar[16];                 // grp1: R accumulator, lives until P9

        // ---- P4: grp0 = gate cumsum part 1 | grp1 = V proj (cc 0..31) ----
        if (grp == 0) {
            const int t0 = th * 16;
            #pragma unroll
            for (int t = 0; t < 16; ++t) t16[t] = 0.0f;
            for (int mm = 0; mm < 32; ++mm) {
                const float w = Wg2[mm * 256 + d];
                #pragma unroll
                for (int i = 0; i < 4; ++i) {
                    float4 f4 = *(const float4*)&fw1t[mm][t0 + 4 * i];
                    t16[4*i+0] += f4.x * w; t16[4*i+1] += f4.y * w;
                    t16[4*i+2] += f4.z * w; t16[4*i+3] += f4.w * w;
                }
            }
            float r = 0.0f;
            #pragma unroll
            for (int t = 0; t < 16; ++t) {
                if ((l0 + t0 + t) < L) r += logsig(t16[t]) * (1.0f / 32.0f);
                t16[t] = r;                    // local cumsum
            }
            if (th == 0) gcarry[d] = r;
        } else {
            const int t0 = th * 16;
            #pragma unroll
            for (int t = 0; t < 16; ++t) t16[t] = 0.0f;
            for (int cc = 0; cc < 32; ++cc) {
                float col[17];
                #pragma unroll
                for (int i = 0; i < 4; ++i) {
                    float4 c4 = *(const float4*)&sxc[cc][t0 + 4 * i];
                    col[4*i] = c4.x; col[4*i+1] = c4.y; col[4*i+2] = c4.z; col[4*i+3] = c4.w;
                }
                col[16] = sxc[cc][t0 + 16];
                const float wv0 = Wv[(2*cc)*256 + d], wv1 = Wv[(2*cc+1)*256 + d];
                #pragma unroll
                for (int t = 0; t < 16; ++t) t16[t] += col[t] * wv0 + col[t+1] * wv1;
            }
        }
        __syncthreads();

        // ---- P5: grp0 = finish gate + Q/K proj | grp1 = V (cc 32..63) + store + R proj ----
        if (grp == 0) {
            const int t0 = th * 16;
            const float c = (th == 0) ? 0.0f : gcarry[d];
            #pragma unroll
            for (int t = 0; t < 16; ++t) t16[t] += c;    // full cumsum
            if (th == 1) egl[d] = __expf(t16[15]);
            float aq[16], ak[16];
            #pragma unroll
            for (int t = 0; t < 16; ++t) { aq[t] = 0.0f; ak[t] = 0.0f; }
            for (int cc = 0; cc < 64; ++cc) {
                float col[17];
                #pragma unroll
                for (int i = 0; i < 4; ++i) {
                    float4 c4 = *(const float4*)&sxc[cc][t0 + 4 * i];
                    col[4*i] = c4.x; col[4*i+1] = c4.y; col[4*i+2] = c4.z; col[4*i+3] = c4.w;
                }
                col[16] = sxc[cc][t0 + 16];
                const float wq0 = Wq[(2*cc)*256 + d], wq1 = Wq[(2*cc+1)*256 + d];
                const float wk0 = Wk[(2*cc)*256 + d], wk1 = Wk[(2*cc+1)*256 + d];
                #pragma unroll
                for (int t = 0; t < 16; ++t) {
                    aq[t] += col[t] * wq0 + col[t+1] * wq1;
                    ak[t] += col[t] * wk0 + col[t+1] * wk1;
                }
            }
            #pragma unroll
            for (int t = 0; t < 16; ++t) {
                bool valid = (l0 + t0 + t) < L;
                float ep = __expf(t16[t]);
                float em = __expf(-t16[t]);
                qf[t0 + t][d] = valid ? aq[t] * 0.125f * ep : 0.0f;
                kf[t0 + t][d] = valid ? ak[t] * em : 0.0f;
            }
        } else {
            const int t0 = th * 16;
            for (int cc = 32; cc < 64; ++cc) {
                float col[17];
                #pragma unroll
                for (int i = 0; i < 4; ++i) {
                    float4 c4 = *(const float4*)&sxc[cc][t0 + 4 * i];
                    col[4*i] = c4.x; col[4*i+1] = c4.y; col[4*i+2] = c4.z; col[4*i+3] = c4.w;
                }
                col[16] = sxc[cc][t0 + 16];
                const float wv0 = Wv[(2*cc)*256 + d], wv1 = Wv[(2*cc+1)*256 + d];
                #pragma unroll
                for (int t = 0; t < 16; ++t) t16[t] += col[t] * wv0 + col[t+1] * wv1;
            }
            #pragma unroll
            for (int t = 0; t < 16; ++t)
                voc[t0 + t][d] = ((l0 + t0 + t) < L) ? t16[t] : 0.0f;
            // R projection; result applied to voc at P9
            #pragma unroll
            for (int t = 0; t < 16; ++t) ar[t] = 0.0f;
            for (int cc = 0; cc < 64; ++cc) {
                float col[17];
                #pragma unroll
                for (int i = 0; i < 4; ++i) {
                    float4 c4 = *(const float4*)&sxc[cc][t0 + 4 * i];
                    col[4*i] = c4.x; col[4*i+1] = c4.y; col[4*i+2] = c4.z; col[4*i+3] = c4.w;
                }
                col[16] = sxc[cc][t0 + 16];
                const float w0 = Wr[(2*cc)*256 + d], w1 = Wr[(2*cc+1)*256 + d];
                #pragma unroll
                for (int t = 0; t < 16; ++t) ar[t] += col[t] * w0 + col[t+1] * w1;
            }
        }
        __syncthreads();               // qf, kf, voc ready

        // ---- P6: grp0 = vcol snapshot + triangular scores | grp1 = prefetch issue ----
        float vcol[32];                // grp0
        float pre[5];                  // grp1 staging regs
        if (grp == 0) {
            const int base = h * 64;
            #pragma unroll
            for (int t = 0; t < 32; ++t) vcol[t] = voc[t][base + lane];
            for (int pi = lane + 64 * kh; pi < 528; pi += 128) {
                float fpi = (float)pi;
                int t = (int)((sqrtf(8.0f * fpi + 1.0f) - 1.0f) * 0.5f);
                if (((t + 1) * (t + 2)) / 2 <= pi) ++t;
                if ((t * (t + 1)) / 2 > pi) --t;
                int s = pi - (t * (t + 1)) / 2;
                float a = 0.0f;
                #pragma unroll
                for (int ii = 0; ii < 16; ++ii) {
                    int i = (ii + lane) & 15;
                    float4 q4 = *(const float4*)&qf[t][base + 4 * i];
                    float4 k4 = *(const float4*)&kf[s][base + 4 * i];
                    a += q4.x*k4.x + q4.y*k4.y + q4.z*k4.z + q4.w*k4.w;
                }
                Ats[h * 1152 + t * 36 + s] = a;
            }
        } else if (ch + 1 < NC) {
            const int l0n = l0 + 32;
            #pragma unroll
            for (int k = 0; k < 5; ++k) {
                int idx = t512 + k * 512;
                if (idx < 64 * 33) {
                    int cc = idx / 33, i = idx - cc * 33;
                    int p = l0n + i; if (p > SLEN - 1) p = SLEN - 1;
                    pre[k] = src[cbase + cc * 32768 + p * PSTRIDE];
                }
            }
        }
        __syncthreads();               // Ats ready; vcol snapped (voc dead as v)

        // ---- P7: kh1 = o_inter partial (pre-update S rows 32..63) -> voc
        //          | grp1 = write prefetched slab into sxc (sxc dead since P5) ----
        if (grp == 0) {
            if (kh == 1) {
                const int base = h * 64;
                #pragma unroll
                for (int t = 0; t < 32; ++t) {
                    float oe = 0.0f;
                    #pragma unroll
                    for (int i = 0; i < 8; ++i) {
                        float4 q4 = *(const float4*)&qf[t][base + 32 + 4 * i];
                        oe += q4.x*S[4*i] + q4.y*S[4*i+1] + q4.z*S[4*i+2] + q4.w*S[4*i+3];
                    }
                    voc[t][base + lane] = oe;
                }
            }
        } else if (ch + 1 < NC) {
            #pragma unroll
            for (int k = 0; k < 5; ++k) {
                int idx = t512 + k * 512;
                if (idx < 64 * 33) {
                    int cc = idx / 33, i = idx - cc * 33;
                    sxc[cc][i] = pre[k];
                }
            }
        }
        __syncthreads();               // oe1 partials in voc; next slab in sxc

        // ---- P8: kh0 = finalize o (oe0 + o_intra + RMS) | kh1 = S update rows 32..63
        //          | grp1 = LN stats for next chunk ----
        if (grp == 0) {
            const int base = h * 64;
            if (kh == 0) {
                #pragma unroll
                for (int t = 0; t < 32; ++t) {
                    float ot = voc[t][base + lane];
                    #pragma unroll
                    for (int i = 0; i < 8; ++i) {
                        float4 q4 = *(const float4*)&qf[t][base + 4 * i];
                        ot += q4.x*S[4*i] + q4.y*S[4*i+1] + q4.z*S[4*i+2] + q4.w*S[4*i+3];
                    }
                    const float* arow = &Ats[h * 1152 + t * 36];
                    #pragma unroll
                    for (int s4 = 0; s4 + 4 <= t + 1; s4 += 4) {
                        float4 a4 = *(const float4*)&arow[s4];
                        ot += a4.x*vcol[s4] + a4.y*vcol[s4+1] + a4.z*vcol[s4+2] + a4.w*vcol[s4+3];
                    }
                    #pragma unroll
                    for (int s = (t + 1) & ~3; s <= t; ++s) ot += arow[s] * vcol[s];
                    float ss = ot * ot;
                    #pragma unroll
                    for (int off = 32; off > 0; off >>= 1) ss += __shfl_xor(ss, off, 64);
                    voc[t][base + lane] = ot * rsqrtf(ss * (1.0f / 64.0f) + EPS) * gnv;
                }
            } else {
                const int kb = base + 32;
                #pragma unroll
                for (int i = 0; i < 8; ++i) {
                    float s0 = 0.0f, s1 = 0.0f, s2 = 0.0f, s3 = 0.0f;
                    #pragma unroll
                    for (int t = 0; t < 32; ++t) {
                        float4 k4 = *(const float4*)&kf[t][kb + 4 * i];
                        const float vt = vcol[t];
                        s0 += k4.x * vt; s1 += k4.y * vt; s2 += k4.z * vt; s3 += k4.w * vt;
                    }
                    S[4*i+0] = egl[kb + 4*i+0] * (S[4*i+0] + s0);
                    S[4*i+1] = egl[kb + 4*i+1] * (S[4*i+1] + s1);
                    S[4*i+2] = egl[kb + 4*i+2] * (S[4*i+2] + s2);
                    S[4*i+3] = egl[kb + 4*i+3] * (S[4*i+3] + s3);
                }
            }
        } else if (ch + 1 < NC) {
            for (int col = wv - 8; col < 33; col += 8) {
                float x = sxc[lane][col];
                float s1 = x, s2 = x * x;
                #pragma unroll
                for (int off = 32; off > 0; off >>= 1) {
                    s1 += __shfl_xor(s1, off, 64);
                    s2 += __shfl_xor(s2, off, 64);
                }
                if (lane == 0) {
                    float mu  = s1 * (1.0f / 64.0f);
                    float var = s2 * (1.0f / 64.0f) - mu * mu;
                    smu[col]  = mu;
                    sinv[col] = rsqrtf(fmaxf(var, 0.0f) + EPS);
                }
            }
        }
        __syncthreads();               // final o in voc

        // ---- P9: kh0 = S update rows 0..31 | grp1 = voc *= silu(r) ----
        if (grp == 0) {
            if (kh == 0) {
                const int kb = h * 64;
                #pragma unroll
                for (int i = 0; i < 8; ++i) {
                    float s0 = 0.0f, s1 = 0.0f, s2 = 0.0f, s3 = 0.0f;
                    #pragma unroll
                    for (int t = 0; t < 32; ++t) {
                        float4 k4 = *(const float4*)&kf[t][kb + 4 * i];
                        const float vt = vcol[t];
                        s0 += k4.x * vt; s1 += k4.y * vt; s2 += k4.z * vt; s3 += k4.w * vt;
                    }
                    S[4*i+0] = egl[kb + 4*i+0] * (S[4*i+0] + s0);
                    S[4*i+1] = egl[kb + 4*i+1] * (S[4*i+1] + s1);
                    S[4*i+2] = egl[kb + 4*i+2] * (S[4*i+2] + s2);
                    S[4*i+3] = egl[kb + 4*i+3] * (S[4*i+3] + s3);
                }
            }
        } else {
            const int t0 = th * 16;
            #pragma unroll
            for (int t = 0; t < 16; ++t) {
                const float r = ar[t];
                voc[t0 + t][d] *= r / (1.0f + __expf(-r));
            }
        }
        __syncthreads();               // voc = o * silu(r)

        // ---- P10: gdec = oc @ Wo (1024 threads: 1 col x 4 rows each) ----
        {
            const int m2 = tid & 127;
            const int rg = tid >> 7;         // 0..7
            float acc[4] = {0, 0, 0, 0};
            for (int j = 0; j < 256; j += 4) {
                float w0 = Wo[(j+0)*128 + m2];
                float w1 = Wo[(j+1)*128 + m2];
                float w2 = Wo[(j+2)*128 + m2];
                float w3 = Wo[(j+3)*128 + m2];
                #pragma unroll
                for (int i = 0; i < 4; ++i) {
                    float4 o4 = *(const float4*)&voc[rg * 4 + i][j];
                    acc[i] += o4.x*w0 + o4.y*w1 + o4.z*w2 + o4.w*w3;
                }
            }
            #pragma unroll
            for (int i = 0; i < 4; ++i)
                gdec[(rg * 4 + i) * 132 + m2] = acc[i];
        }
        __syncthreads();

        // ---- P11: deconv1d (K=2) + bias + residual + store (2 rows/thread) ----
        {
            const int o  = tid & 63;
            const int pg = tid >> 6;         // 0..15 -> rows pg*2, pg*2+1
            const float2* ctw2 = (const float2*)ctw;
            float a0 = 0.0f, a1 = 0.0f;
            for (int c4 = 0; c4 < 128; c4 += 4) {
                float2 w0 = ctw2[(c4+0)*64 + o];
                float2 w1 = ctw2[(c4+1)*64 + o];
                float2 w2 = ctw2[(c4+2)*64 + o];
                float2 w3 = ctw2[(c4+3)*64 + o];
                float4 rm = (pg == 0) ? *(const float4*)&gprevs[c4]
                                      : *(const float4*)&gdec[(pg*2 - 1) * 132 + c4];
                float4 r0 = *(const float4*)&gdec[(pg*2 + 0) * 132 + c4];
                float4 r1 = *(const float4*)&gdec[(pg*2 + 1) * 132 + c4];
                a0 += r0.x*w0.x + rm.x*w0.y + r0.y*w1.x + rm.y*w1.y
                    + r0.z*w2.x + rm.z*w2.y + r0.w*w3.x + rm.w*w3.y;
                a1 += r1.x*w0.x + r0.x*w0.y + r1.y*w1.x + r0.y*w1.y
                    + r1.z*w2.x + r0.z*w2.y + r1.w*w3.x + r0.w*w3.y;
            }
            const int tl = pg * 2;
            out[cbase + o * 32768 + (l0 + tl    ) * PSTRIDE] = a0 + bias + sxr[o][tl];
            out[cbase + o * 32768 + (l0 + tl + 1) * PSTRIDE] = a1 + bias + sxr[o][tl + 1];
        }
        __syncthreads();
        if (tid < 128) gprevs[tid] = gdec[31 * 132 + tid];
    }
}

extern "C" void kernel_launch(void* const* d_in, const int* in_sizes, int n_in,
                              void* d_out, int out_size, void* d_ws, size_t ws_size,
                              hipStream_t stream)
{
    const float* x = (const float*)d_in[0];
    float* y = (float*)d_ws;     // intra output: 4*64*256*128 fp32
    float* z = (float*)d_out;

    gla_pass<128, 1><<<dim3(1024), dim3(1024), 0, stream>>>(
        x, y,
        (const float*)d_in[2],  (const float*)d_in[3],  (const float*)d_in[4],
        (const float*)d_in[5],  (const float*)d_in[6],  (const float*)d_in[7],
        (const float*)d_in[8],  (const float*)d_in[9],  (const float*)d_in[10],
        (const float*)d_in[11], (const float*)d_in[12], (const float*)d_in[13]);

    gla_pass<256, 128><<<dim3(512), dim3(1024), 0, stream>>>(
        y, z,
        (const float*)d_in[14], (const float*)d_in[15], (const float*)d_in[16],
        (const float*)d_in[17], (const float*)d_in[18], (const float*)d_in[19],
        (const float*)d_in[20], (const float*)d_in[21], (const float*)d_in[22],
        (const float*)d_in[23], (const float*)d_in[24], (const float*)d_in[25]);
}

// Round 3
// 5908.994 us; speedup vs baseline: 2.7334x; 2.7130x over previous
//
#include <hip/hip_runtime.h>

#define EPS 1e-5f

__device__ __forceinline__ float logsig(float z) {
    return fminf(z, 0.0f) - log1pf(__expf(-fabsf(z)));
}

// One block = one sequence. 512 threads = 8 waves.
// Head h = wave&3; k-half kh = wave>>2 (kh0 holds S rows 0..31, kh1 rows 32..63).
// PSTRIDE==1  : intra pass (seq over q, SLEN=128); PSTRIDE==128: inter pass (SLEN=256)
// Empirical RA law on this backend (R0/R1/R2): VGPR cap = 2048/(2*waves_per_wg)
// regardless of LDS or waves_per_eu attributes -> 512 thr = 128 regs (1024 thr = 64,
// which spilled catastrophically in R1/R2). So stay at 512 threads.
// R3 changes vs the 7589us baseline:
//  - Ats/gdec overlaid in `uni` (never live simultaneously) -> frees 16.9 KB.
//  - Double-buffered slab (sxA/sxB): next chunk's slab loaded into regs (pre[5])
//    at chunk start, ds-written to the idle buffer after the gate stage (T14
//    issue-early/write-late). Removes the serial load->LDS->barrier A-stage.
//  - LN stats wave-parallel (8 waves x shfl_xor tree) instead of 33 serial threads.
template<int SLEN, int PSTRIDE>
__global__ __launch_bounds__(512)
__attribute__((amdgpu_waves_per_eu(2, 2)))
void gla_pass(const float* __restrict__ src, float* __restrict__ out,
              const float* __restrict__ gamma, const float* __restrict__ beta,
              const float* __restrict__ Wq, const float* __restrict__ Wk,
              const float* __restrict__ Wv, const float* __restrict__ Wg1,
              const float* __restrict__ Wg2, const float* __restrict__ Wr,
              const float* __restrict__ gn, const float* __restrict__ Wo,
              const float* __restrict__ ctw, const float* __restrict__ ctb)
{
    constexpr int NC = SLEN / 32;
    constexpr int L  = SLEN - 1;

    __shared__ __align__(16) float sxA[64][36];   // slab buffer A (33 cols used)
    __shared__ __align__(16) float sxB[64][36];   // slab buffer B
    __shared__ __align__(16) float sxr[64][32];   // raw slab (residual source)
    __shared__ __align__(16) float qf[32][256];   // q*Dk^-0.5 * exp(gc)
    __shared__ __align__(16) float kf[32][256];   // k * exp(-gc)
    __shared__ __align__(16) float voc[32][256];  // v -> oe1 partial -> o -> o*silu(r)
    __shared__ __align__(16) float uni[4608];     // Ats[4][32][36] OVERLAID with gdec[32][132]
    __shared__ __align__(16) float fw1t[32][36];  // (f @ Wg1)^T : fw1t[m][t]
    __shared__ __align__(16) float gprevs[128];   // deconv carry row
    __shared__ float egl[256];                    // exp(chunk-total gate)
    __shared__ float sgam[64], sbet[64];
    __shared__ float smu[33], sinv[33];
    __shared__ float gcarry[256];                 // gate cumsum carry (t=0..15 total)

    float* const Ats  = uni;          // h*1152 + t*36 + s      (live F1 -> F2b)
    float* const gdec = uni;          // row*132 + c            (live H -> I; Ats dead)

    const int tid  = threadIdx.x;
    const int lane = tid & 63;
    const int wv   = tid >> 6;        // 0..7
    const int h    = wv & 3;          // head
    const int kh   = wv >> 2;         // k-half
    const int d    = tid & 255;       // column for t-split stages
    const int th   = (tid >> 8) & 1;  // t-half (rows th*16 .. th*16+15); th == kh
    const int n    = blockIdx.x;

    int b, fixedoff;
    if constexpr (PSTRIDE == 1) { b = n >> 8; fixedoff = (n & 255) * 128; }
    else                        { b = n >> 7; fixedoff = (n & 127); }
    const int cbase = (b * 64) * 32768 + fixedoff;

    if (tid < 64)  { sgam[tid] = gamma[tid]; sbet[tid] = beta[tid]; }
    if (tid < 128) gprevs[tid] = 0.0f;

    float S[32];
    #pragma unroll
    for (int k = 0; k < 32; ++k) S[k] = 0.0f;

    const float gnv  = gn[h * 64 + lane];
    const float bias = ctb[lane];

    // ---- prologue: chunk-0 slab -> sxA (raw) ----
    #pragma unroll
    for (int k = 0; k < 5; ++k) {
        int idx = tid + k * 512;
        if (idx < 64 * 33) {
            int cc = idx / 33, i = idx - cc * 33;
            sxA[cc][i] = src[cbase + cc * 32768 + i * PSTRIDE];
        }
    }

    for (int ch = 0; ch < NC; ++ch) {
        const int l0 = ch * 32;
        float (* const cur)[36] = (ch & 1) ? sxB : sxA;
        float (* const nxt)[36] = (ch & 1) ? sxA : sxB;
        __syncthreads();              // cur(ch) raw ready (prologue or prefetch)

        // ---- A': issue next-chunk slab loads into registers (write to nxt later) ----
        float pre[5];
        const bool pf = (ch + 1 < NC);
        if (pf) {
            const int l0n = l0 + 32;
            #pragma unroll
            for (int k = 0; k < 5; ++k) {
                int idx = tid + k * 512;
                if (idx < 64 * 33) {
                    int cc = idx / 33, i = idx - cc * 33;
                    int p  = l0n + i; if (p > SLEN - 1) p = SLEN - 1;
                    pre[k] = src[cbase + cc * 32768 + p * PSTRIDE];
                }
            }
        }

        // ---- B1: per-column LN stats, wave-parallel (8 waves x shfl tree) ----
        for (int col = wv; col < 33; col += 8) {
            float x = cur[lane][col];
            float s1 = x, s2 = x * x;
            #pragma unroll
            for (int off = 32; off > 0; off >>= 1) {
                s1 += __shfl_xor(s1, off, 64);
                s2 += __shfl_xor(s2, off, 64);
            }
            if (lane == 0) {
                float mu  = s1 * (1.0f / 64.0f);
                float var = s2 * (1.0f / 64.0f) - mu * mu;
                smu[col]  = mu;
                sinv[col] = rsqrtf(fmaxf(var, 0.0f) + EPS);
            }
        }
        __syncthreads();

        // ---- B2: normalize in place, raw copy to sxr fused ----
        #pragma unroll
        for (int k = 0; k < 5; ++k) {
            int idx = tid + k * 512;
            if (idx < 64 * 33) {
                int cc = idx / 33, i = idx - cc * 33;
                float x = cur[cc][i];
                if (i < 32) sxr[cc][i] = x;
                cur[cc][i] = (x - smu[i]) * sinv[i] * sgam[cc] + sbet[cc];
            }
        }
        __syncthreads();

        // ---- gate p1: fw1t[m][t] ----
        {
            const int m = tid & 31, tg2 = tid >> 5;   // tg2 in [0,16)
            float a0 = 0.0f, a1 = 0.0f;
            for (int cc = 0; cc < 64; ++cc) {
                const float w0 = Wg1[(2*cc)*32 + m], w1 = Wg1[(2*cc+1)*32 + m];
                a0 += cur[cc][tg2]      * w0 + cur[cc][tg2 + 1]  * w1;
                a1 += cur[cc][tg2 + 16] * w0 + cur[cc][tg2 + 17] * w1;
            }
            fw1t[m][tg2] = a0; fw1t[m][tg2 + 16] = a1;
        }
        __syncthreads();

        // ---- gate p2: per (col d, t-half) cumsum with carry -> erun/egl ----
        float erunp[16], erunm[16];   // exp(+gc), exp(-gc) for own t-half
        {
            const int t0 = th * 16;
            float acc2[16];
            #pragma unroll
            for (int t = 0; t < 16; ++t) acc2[t] = 0.0f;
            for (int mm = 0; mm < 32; ++mm) {
                const float w = Wg2[mm * 256 + d];
                #pragma unroll
                for (int i = 0; i < 4; ++i) {
                    float4 f4 = *(const float4*)&fw1t[mm][t0 + 4 * i];
                    acc2[4*i+0] += f4.x * w; acc2[4*i+1] += f4.y * w;
                    acc2[4*i+2] += f4.z * w; acc2[4*i+3] += f4.w * w;
                }
            }
            float r = 0.0f;
            #pragma unroll
            for (int t = 0; t < 16; ++t) {
                if ((l0 + t0 + t) < L) r += logsig(acc2[t]) * (1.0f / 32.0f);
                acc2[t] = r;                    // reuse as cumsum store
            }
            if (th == 0) gcarry[d] = r;
            __syncthreads();
            const float c = (th == 0) ? 0.0f : gcarry[d];
            #pragma unroll
            for (int t = 0; t < 16; ++t) {
                float run = c + acc2[t];
                erunp[t] = __expf(run);
                erunm[t] = __expf(-run);
            }
            if (th == 1) egl[d] = erunp[15];
        }

        // ---- A'': write prefetched slab into nxt (loads returned long ago;
        //          nxt is untouched until next chunk's loop-top barrier) ----
        if (pf) {
            #pragma unroll
            for (int k = 0; k < 5; ++k) {
                int idx = tid + k * 512;
                if (idx < 64 * 33) {
                    int cc = idx / 33, i = idx - cc * 33;
                    nxt[cc][i] = pre[k];
                }
            }
        }

        // ---- C: projections; (q,k) fused then v; gate folded at store ----
        {
            const int t0 = th * 16;
            float aq[16], ak[16];
            #pragma unroll
            for (int t = 0; t < 16; ++t) { aq[t] = 0.0f; ak[t] = 0.0f; }
            for (int cc = 0; cc < 64; ++cc) {
                float col[17];
                #pragma unroll
                for (int i = 0; i < 4; ++i) {
                    float4 c4 = *(const float4*)&cur[cc][t0 + 4 * i];
                    col[4*i] = c4.x; col[4*i+1] = c4.y; col[4*i+2] = c4.z; col[4*i+3] = c4.w;
                }
                col[16] = cur[cc][t0 + 16];
                const float wq0 = Wq[(2*cc)*256 + d], wq1 = Wq[(2*cc+1)*256 + d];
                const float wk0 = Wk[(2*cc)*256 + d], wk1 = Wk[(2*cc+1)*256 + d];
                #pragma unroll
                for (int t = 0; t < 16; ++t) {
                    aq[t] += col[t] * wq0 + col[t+1] * wq1;
                    ak[t] += col[t] * wk0 + col[t+1] * wk1;
                }
            }
            #pragma unroll
            for (int t = 0; t < 16; ++t) {
                bool valid = (l0 + t0 + t) < L;
                qf[t0 + t][d] = valid ? aq[t] * 0.125f * erunp[t] : 0.0f;
                kf[t0 + t][d] = valid ? ak[t] * erunm[t] : 0.0f;
            }
        }
        {
            const int t0 = th * 16;
            float av[16];
            #pragma unroll
            for (int t = 0; t < 16; ++t) av[t] = 0.0f;
            for (int cc = 0; cc < 64; ++cc) {
                float col[17];
                #pragma unroll
                for (int i = 0; i < 4; ++i) {
                    float4 c4 = *(const float4*)&cur[cc][t0 + 4 * i];
                    col[4*i] = c4.x; col[4*i+1] = c4.y; col[4*i+2] = c4.z; col[4*i+3] = c4.w;
                }
                col[16] = cur[cc][t0 + 16];
                const float wv0 = Wv[(2*cc)*256 + d], wv1 = Wv[(2*cc+1)*256 + d];
                #pragma unroll
                for (int t = 0; t < 16; ++t) av[t] += col[t] * wv0 + col[t+1] * wv1;
            }
            #pragma unroll
            for (int t = 0; t < 16; ++t)
                voc[t0 + t][d] = ((l0 + t0 + t) < L) ? av[t] : 0.0f;
        }
        __syncthreads();

        // ---- F: attention; 2 waves per head ----
        const int base = h * 64;
        float vcol[32];
        #pragma unroll
        for (int t = 0; t < 32; ++t) vcol[t] = voc[t][base + lane];

        // F1: triangular scores, 128 lanes per head
        for (int pi = lane + 64 * kh; pi < 528; pi += 128) {
            float fpi = (float)pi;
            int t = (int)((sqrtf(8.0f * fpi + 1.0f) - 1.0f) * 0.5f);
            if (((t + 1) * (t + 2)) / 2 <= pi) ++t;
            if ((t * (t + 1)) / 2 > pi) --t;
            int s = pi - (t * (t + 1)) / 2;
            float a = 0.0f;
            #pragma unroll
            for (int ii = 0; ii < 16; ++ii) {
                int i = (ii + lane) & 15;
                float4 q4 = *(const float4*)&qf[t][base + 4 * i];
                float4 k4 = *(const float4*)&kf[s][base + 4 * i];
                a += q4.x*k4.x + q4.y*k4.y + q4.z*k4.z + q4.w*k4.w;
            }
            Ats[h * 1152 + t * 36 + s] = a;
        }
        __syncthreads();   // A: Ats ready; all vcol snapshots done (voc dead as v)

        // F2a: kh1 writes o_inter partial (vs pre-update S rows 32..63) into voc
        if (kh == 1) {
            #pragma unroll
            for (int t = 0; t < 32; ++t) {
                float oe = 0.0f;
                #pragma unroll
                for (int i = 0; i < 8; ++i) {
                    float4 q4 = *(const float4*)&qf[t][base + 32 + 4 * i];
                    oe += q4.x*S[4*i] + q4.y*S[4*i+1] + q4.z*S[4*i+2] + q4.w*S[4*i+3];
                }
                voc[t][base + lane] = oe;
            }
        }
        __syncthreads();   // B: oe1 partials in voc

        if (kh == 0) {
            // F2b: o = oe0 + oe1 + o_intra, RMS-norm, final o into voc
            #pragma unroll
            for (int t = 0; t < 32; ++t) {
                float ot = voc[t][base + lane];
                #pragma unroll
                for (int i = 0; i < 8; ++i) {
                    float4 q4 = *(const float4*)&qf[t][base + 4 * i];
                    ot += q4.x*S[4*i] + q4.y*S[4*i+1] + q4.z*S[4*i+2] + q4.w*S[4*i+3];
                }
                const float* arow = &Ats[h * 1152 + t * 36];
                #pragma unroll
                for (int s4 = 0; s4 + 4 <= t + 1; s4 += 4) {
                    float4 a4 = *(const float4*)&arow[s4];
                    ot += a4.x*vcol[s4] + a4.y*vcol[s4+1] + a4.z*vcol[s4+2] + a4.w*vcol[s4+3];
                }
                #pragma unroll
                for (int s = (t + 1) & ~3; s <= t; ++s) ot += arow[s] * vcol[s];
                float ss = ot * ot;
                #pragma unroll
                for (int off = 32; off > 0; off >>= 1) ss += __shfl_xor(ss, off, 64);
                voc[t][base + lane] = ot * rsqrtf(ss * (1.0f / 64.0f) + EPS) * gnv;
            }
        } else {
            // kh1: F4 state update rows 32..63 (overlaps kh0's F2b)
            const int kb = base + 32;
            #pragma unroll
            for (int i = 0; i < 8; ++i) {
                float s0 = 0.0f, s1 = 0.0f, s2 = 0.0f, s3 = 0.0f;
                #pragma unroll
                for (int t = 0; t < 32; ++t) {
                    float4 k4 = *(const float4*)&kf[t][kb + 4 * i];
                    const float vt = vcol[t];
                    s0 += k4.x * vt; s1 += k4.y * vt; s2 += k4.z * vt; s3 += k4.w * vt;
                }
                S[4*i+0] = egl[kb + 4*i+0] * (S[4*i+0] + s0);
                S[4*i+1] = egl[kb + 4*i+1] * (S[4*i+1] + s1);
                S[4*i+2] = egl[kb + 4*i+2] * (S[4*i+2] + s2);
                S[4*i+3] = egl[kb + 4*i+3] * (S[4*i+3] + s3);
            }
        }
        __syncthreads();   // C: final o in voc; kh0 may now update S

        if (kh == 0) {
            // F4 state update rows 0..31 (overlaps kh1's half of G)
            const int kb = base;
            #pragma unroll
            for (int i = 0; i < 8; ++i) {
                float s0 = 0.0f, s1 = 0.0f, s2 = 0.0f, s3 = 0.0f;
                #pragma unroll
                for (int t = 0; t < 32; ++t) {
                    float4 k4 = *(const float4*)&kf[t][kb + 4 * i];
                    const float vt = vcol[t];
                    s0 += k4.x * vt; s1 += k4.y * vt; s2 += k4.z * vt; s3 += k4.w * vt;
                }
                S[4*i+0] = egl[kb + 4*i+0] * (S[4*i+0] + s0);
                S[4*i+1] = egl[kb + 4*i+1] * (S[4*i+1] + s1);
                S[4*i+2] = egl[kb + 4*i+2] * (S[4*i+2] + s2);
                S[4*i+3] = egl[kb + 4*i+3] * (S[4*i+3] + s3);
            }
        }

        // ---- G: r = f @ Wr ; voc *= silu(r) ----
        {
            const int t0 = th * 16;
            float ar[16];
            #pragma unroll
            for (int t = 0; t < 16; ++t) ar[t] = 0.0f;
            for (int cc = 0; cc < 64; ++cc) {
                float col[17];
                #pragma unroll
                for (int i = 0; i < 4; ++i) {
                    float4 c4 = *(const float4*)&cur[cc][t0 + 4 * i];
                    col[4*i] = c4.x; col[4*i+1] = c4.y; col[4*i+2] = c4.z; col[4*i+3] = c4.w;
                }
                col[16] = cur[cc][t0 + 16];
                const float w0 = Wr[(2*cc)*256 + d], w1 = Wr[(2*cc+1)*256 + d];
                #pragma unroll
                for (int t = 0; t < 16; ++t) ar[t] += col[t] * w0 + col[t+1] * w1;
            }
            #pragma unroll
            for (int t = 0; t < 16; ++t) {
                const float r = ar[t];
                voc[t0 + t][d] *= r / (1.0f + __expf(-r));
            }
        }
        __syncthreads();

        // ---- H: gdec = oc @ Wo ; thread = (m2 in [0,64), 2 cols, 4 rows) ----
        // (gdec overlays Ats: Ats last read was F2b, two barriers ago)
        {
            const int m2  = tid & 63;
            const int tg4 = tid >> 6;        // 0..7 -> rows tg4*4..+3
            float accA[4] = {0,0,0,0}, accB[4] = {0,0,0,0};
            for (int j = 0; j < 256; j += 4) {
                float wA0 = Wo[(j+0)*128 + m2],      wB0 = Wo[(j+0)*128 + m2 + 64];
                float wA1 = Wo[(j+1)*128 + m2],      wB1 = Wo[(j+1)*128 + m2 + 64];
                float wA2 = Wo[(j+2)*128 + m2],      wB2 = Wo[(j+2)*128 + m2 + 64];
                float wA3 = Wo[(j+3)*128 + m2],      wB3 = Wo[(j+3)*128 + m2 + 64];
                #pragma unroll
                for (int i = 0; i < 4; ++i) {
                    float4 o4 = *(const float4*)&voc[tg4 * 4 + i][j];
                    accA[i] += o4.x*wA0 + o4.y*wA1 + o4.z*wA2 + o4.w*wA3;
                    accB[i] += o4.x*wB0 + o4.y*wB1 + o4.z*wB2 + o4.w*wB3;
                }
            }
            #pragma unroll
            for (int i = 0; i < 4; ++i) {
                gdec[(tg4 * 4 + i) * 132 + m2]      = accA[i];
                gdec[(tg4 * 4 + i) * 132 + m2 + 64] = accB[i];
            }
        }
        __syncthreads();

        // ---- I: deconv1d (K=2) + bias + residual (from sxr) + store ----
        {
            const int o  = lane;
            const int pg = wv;               // 0..7 -> rows pg*4..+3
            const float2* ctw2 = (const float2*)ctw;   // [cin][o] -> (w_k0, w_k1)
            float acc4[4] = {0,0,0,0};
            for (int c4 = 0; c4 < 128; c4 += 4) {
                float2 w0 = ctw2[(c4+0)*64 + o];
                float2 w1 = ctw2[(c4+1)*64 + o];
                float2 w2 = ctw2[(c4+2)*64 + o];
                float2 w3 = ctw2[(c4+3)*64 + o];
                float4 r[5];
                r[0] = (pg == 0) ? *(const float4*)&gprevs[c4]
                                 : *(const float4*)&gdec[(pg*4 - 1) * 132 + c4];
                #pragma unroll
                for (int j = 0; j < 4; ++j)
                    r[j+1] = *(const float4*)&gdec[(pg*4 + j) * 132 + c4];
                #pragma unroll
                for (int i = 0; i < 4; ++i) {
                    acc4[i] += r[i+1].x*w0.x + r[i].x*w0.y
                             + r[i+1].y*w1.x + r[i].y*w1.y
                             + r[i+1].z*w2.x + r[i].z*w2.y
                             + r[i+1].w*w3.x + r[i].w*w3.y;
                }
            }
            #pragma unroll
            for (int i = 0; i < 4; ++i) {
                const int tl = pg * 4 + i;
                const int oi = cbase + o * 32768 + (l0 + tl) * PSTRIDE;
                out[oi] = acc4[i] + bias + sxr[o][tl];
            }
        }
        __syncthreads();
        if (tid < 128) gprevs[tid] = gdec[31 * 132 + tid];
    }
}

extern "C" void kernel_launch(void* const* d_in, const int* in_sizes, int n_in,
                              void* d_out, int out_size, void* d_ws, size_t ws_size,
                              hipStream_t stream)
{
    const float* x = (const float*)d_in[0];
    float* y = (float*)d_ws;     // intra output: 4*64*256*128 fp32
    float* z = (float*)d_out;

    gla_pass<128, 1><<<dim3(1024), dim3(512), 0, stream>>>(
        x, y,
        (const float*)d_in[2],  (const float*)d_in[3],  (const float*)d_in[4],
        (const float*)d_in[5],  (const float*)d_in[6],  (const float*)d_in[7],
        (const float*)d_in[8],  (const float*)d_in[9],  (const float*)d_in[10],
        (const float*)d_in[11], (const float*)d_in[12], (const float*)d_in[13]);

    gla_pass<256, 128><<<dim3(512), dim3(512), 0, stream>>>(
        y, z,
        (const float*)d_in[14], (const float*)d_in[15], (const float*)d_in[16],
        (const float*)d_in[17], (const float*)d_in[18], (const float*)d_in[19],
        (const float*)d_in[20], (const float*)d_in[21], (const float*)d_in[22],
        (const float*)d_in[23], (const float*)d_in[24], (const float*)d_in[25]);
}